// Round 5
// baseline (135.604 us; speedup 1.0000x reference)
//
#include <hip/hip_runtime.h>

#define NDIM 64   // D
#define FDIM 128  // 2D
#define LSTRIDE 136  // node-kernel LDS row stride in halfs (128 + 8 pad)
#define YSTR 72      // edge-kernel LDS row stride in halfs (64 + 8 pad -> 144 B)

typedef _Float16 half8  __attribute__((ext_vector_type(8)));
typedef _Float16 half4v __attribute__((ext_vector_type(4)));
typedef float    float4v __attribute__((ext_vector_type(4)));

// ---------------------------------------------------------------------------
// Kernel 1 (v5, UNCHANGED from R4): node half-layers via MFMA; 32 nodes/wave.
//   Yab[n][j]    = b1[j] + sum_k x[n][k] * W1[j][k]        (j < 64)
//   Yab[n][64+j] =         sum_k x[n][k] * W1[j][64+k]
// ---------------------------------------------------------------------------
__global__ __launch_bounds__(256) void node_gemm_kernel(
    const float* __restrict__ x,        // [N][64]
    const float* __restrict__ W1,       // [64][128]
    const float* __restrict__ b1,       // [64]
    _Float16* __restrict__ Yab,         // [N][128]
    int N)
{
    __shared__ _Float16 lds[4][16 * LSTRIDE];   // per-wave transpose slice

    const int wave = threadIdx.x >> 6;
    const int lane = threadIdx.x & 63;
    const int c = lane & 15;   // A: j-in-tile | B/C: node-in-tile
    const int g = lane >> 4;   // k-group / C row-group

    const int node0 = (blockIdx.x * 4 + wave) * 32;   // 32 nodes per wave
    if (node0 >= N) return;    // wave-uniform; no barriers in this kernel

    half8 Bf[2][2];   // [tile][kk]
    #pragma unroll
    for (int t2 = 0; t2 < 2; t2++) {
        #pragma unroll
        for (int kk = 0; kk < 2; kk++) {
            const float* bp = x + (size_t)(node0 + t2 * 16 + c) * NDIM
                              + kk * 32 + g * 8;
            float4v b0 = __builtin_nontemporal_load((const float4v*)bp);
            float4v b1v_ = __builtin_nontemporal_load((const float4v*)(bp + 4));
            half8 B;
            B[0] = (_Float16)b0[0]; B[1] = (_Float16)b0[1];
            B[2] = (_Float16)b0[2]; B[3] = (_Float16)b0[3];
            B[4] = (_Float16)b1v_[0]; B[5] = (_Float16)b1v_[1];
            B[6] = (_Float16)b1v_[2]; B[7] = (_Float16)b1v_[3];
            Bf[t2][kk] = B;
        }
    }

    float4v C[2][8];
    #pragma unroll
    for (int t2 = 0; t2 < 2; t2++)
        #pragma unroll
        for (int mt = 0; mt < 8; mt++)
            C[t2][mt] = (float4v){0.f, 0.f, 0.f, 0.f};

    #pragma unroll
    for (int kk = 0; kk < 2; kk++) {
        #pragma unroll
        for (int mt = 0; mt < 8; mt++) {
            const float* wp = (mt < 4)
                ? (W1 + (size_t)(mt * 16 + c) * FDIM + kk * 32 + g * 8)
                : (W1 + (size_t)((mt - 4) * 16 + c) * FDIM + NDIM + kk * 32 + g * 8);
            float4v a0 = *(const float4v*)wp;
            float4v a1 = *(const float4v*)(wp + 4);
            half8 Af;
            Af[0] = (_Float16)a0[0]; Af[1] = (_Float16)a0[1];
            Af[2] = (_Float16)a0[2]; Af[3] = (_Float16)a0[3];
            Af[4] = (_Float16)a1[0]; Af[5] = (_Float16)a1[1];
            Af[6] = (_Float16)a1[2]; Af[7] = (_Float16)a1[3];
            C[0][mt] = __builtin_amdgcn_mfma_f32_16x16x32_f16(Af, Bf[0][kk], C[0][mt], 0, 0, 0);
            C[1][mt] = __builtin_amdgcn_mfma_f32_16x16x32_f16(Af, Bf[1][kk], C[1][mt], 0, 0, 0);
        }
    }

    #pragma unroll
    for (int t2 = 0; t2 < 2; t2++) {
        #pragma unroll
        for (int mt = 0; mt < 8; mt++) {
            float4v badd = (float4v){0.f, 0.f, 0.f, 0.f};
            if (mt < 4) badd = *(const float4v*)(b1 + mt * 16 + g * 4);
            half4v o;
            #pragma unroll
            for (int r = 0; r < 4; r++) o[r] = (_Float16)(C[t2][mt][r] + badd[r]);
            *(half4v*)&lds[wave][c * LSTRIDE + mt * 16 + g * 4] = o;
        }
        #pragma unroll
        for (int p = 0; p < 4; p++) {
            const int node  = 4 * p + (lane >> 4);
            const int chunk = lane & 15;
            half8 v = *(const half8*)&lds[wave][node * LSTRIDE + chunk * 8];
            *(half8*)(Yab + (size_t)(node0 + t2 * 16 + node) * FDIM + chunk * 8) = v;
        }
    }
}

// ---------------------------------------------------------------------------
// Kernel 2 (v4): persistent software-pipelined edge combine.
// R4 showed wave-churn exposes ~600-900 cy of gather latency once per
// 32-edge tile. Now each wave owns ~4 grid-strided tiles and runs a 2-deep
// pipeline: issue gathers(t+1) + indices(t+2), THEN take the vmcnt wait for
// gathers(t) (issued one full iteration earlier), stage to LDS, compute.
// Ping-pong buffers rotated by 2x-unrolled body (static reg indexing).
// Single LDS buffer per wave is safe: DS ops are program-ordered per wave.
//   out[e] = b2 + sum_j W2[j] * relu(Yab[s][j] + Yab[d][64+j])
// ---------------------------------------------------------------------------
#define EDGE_BODY(CURS, CURD, CURSV, CURDV, NXTS, NXTD, NXTSV, NXTDV)           \
    {                                                                           \
        const long tn  = t + stride;                                            \
        const long tnn = tn + stride;                                           \
        if (tn < ntiles) {   /* issue NEXT tile's gathers (no wait) */          \
            _Pragma("unroll")                                                   \
            for (int j = 0; j < 4; j++) {                                       \
                NXTSV[j] = *(const half8*)(Yab + (size_t)NXTS[j] * FDIM + h * 8);            \
                NXTDV[j] = *(const half8*)(Yab + (size_t)NXTD[j] * FDIM + NDIM + h * 8);     \
            }                                                                   \
        }                                                                       \
        if (tnn < ntiles) {  /* issue idx loads for t+2 into cur slots */       \
            _Pragma("unroll")                                                   \
            for (int j = 0; j < 4; j++) {                                       \
                CURS[j] = __builtin_nontemporal_load(ei + tnn * 32 + 8 * j + r8);            \
                CURD[j] = __builtin_nontemporal_load(ei + (size_t)E + tnn * 32 + 8 * j + r8);\
            }                                                                   \
        }                                                                       \
        /* stage current tile to LDS (vmcnt wait lands here, ~1 iter of cover) */            \
        _Pragma("unroll")                                                       \
        for (int j = 0; j < 4; j++) {                                           \
            *(half8*)&lds[wave][(8 * j + r8) * YSTR + h * 8] = CURSV[j];        \
            *(half8*)&lds[wave][(32 + 8 * j + r8) * YSTR + h * 8] = CURDV[j];   \
        }                                                                       \
        const long e0 = t * 32;                                                 \
        _Pragma("unroll")                                                       \
        for (int tt = 0; tt < 2; tt++) {                                        \
            float4v C = (float4v){0.f, 0.f, 0.f, 0.f};                          \
            _Pragma("unroll")                                                   \
            for (int kk = 0; kk < 2; kk++) {                                    \
                half8 A  = *(const half8*)&lds[wave][(tt * 16 + c) * YSTR + kk * 32 + g * 8];      \
                half8 Bv = *(const half8*)&lds[wave][(32 + tt * 16 + c) * YSTR + kk * 32 + g * 8]; \
                half8 H = A + Bv;                         /* v_pk_add_f16 */    \
                H = __builtin_elementwise_max(H, zero8);  /* relu */            \
                C = __builtin_amdgcn_mfma_f32_16x16x32_f16(H, Bw[kk], C, 0, 0, 0);           \
            }                                                                   \
            if (c == 0) {                                                       \
                float4v o;                                                      \
                _Pragma("unroll")                                               \
                for (int r = 0; r < 4; r++) o[r] = C[r] + b2v;                  \
                __builtin_nontemporal_store(o, (float4v*)(out + e0 + tt * 16 + g * 4));      \
            }                                                                   \
        }                                                                       \
    }

__global__ __launch_bounds__(256) void edge_combine_kernel(
    const _Float16* __restrict__ Yab,  // [N][128]
    const int* __restrict__ ei,        // [2E]
    const float* __restrict__ W2,      // [64]
    const float* __restrict__ b2,      // [1]
    float* __restrict__ out,           // [E]
    int E)
{
    __shared__ _Float16 lds[4][64 * YSTR];  // 9.2 KB/wave, 36.9 KB/block

    const int lane = threadIdx.x & 63;
    const int wave = threadIdx.x >> 6;
    const int c  = lane & 15;   // MFMA: edge-in-tile
    const int g  = lane >> 4;   // MFMA: k-group
    const int r8 = lane >> 3;   // gather: row-in-group 0..7
    const int h  = lane & 7;    // gather: 16-B chunk 0..7 within 128-B row

    const long ntiles = (long)E >> 5;                 // 32 edges per tile
    const long stride = (long)gridDim.x * 4;
    long t = (long)blockIdx.x * 4 + wave;
    if (t >= ntiles) return;

    half8 Bw[2];
    #pragma unroll
    for (int kk = 0; kk < 2; kk++) {
        const float* wp = W2 + kk * 32 + g * 8;
        float4v w0 = *(const float4v*)wp;
        float4v w1 = *(const float4v*)(wp + 4);
        half8 B;
        B[0] = (_Float16)w0[0]; B[1] = (_Float16)w0[1];
        B[2] = (_Float16)w0[2]; B[3] = (_Float16)w0[3];
        B[4] = (_Float16)w1[0]; B[5] = (_Float16)w1[1];
        B[6] = (_Float16)w1[2]; B[7] = (_Float16)w1[3];
        Bw[kk] = B;
    }
    const float b2v = b2[0];
    const half8 zero8 = (half8)(_Float16)0.0f;

    // ---- pipeline prologue ----
    int sA[4], dA[4], sB[4], dB[4];
    half8 svA[4], dvA[4], svB[4], dvB[4];

    #pragma unroll
    for (int j = 0; j < 4; j++) {
        sA[j] = __builtin_nontemporal_load(ei + t * 32 + 8 * j + r8);
        dA[j] = __builtin_nontemporal_load(ei + (size_t)E + t * 32 + 8 * j + r8);
    }
    if (t + stride < ntiles) {
        #pragma unroll
        for (int j = 0; j < 4; j++) {
            sB[j] = __builtin_nontemporal_load(ei + (t + stride) * 32 + 8 * j + r8);
            dB[j] = __builtin_nontemporal_load(ei + (size_t)E + (t + stride) * 32 + 8 * j + r8);
        }
    }
    #pragma unroll
    for (int j = 0; j < 4; j++) {
        svA[j] = *(const half8*)(Yab + (size_t)sA[j] * FDIM + h * 8);
        dvA[j] = *(const half8*)(Yab + (size_t)dA[j] * FDIM + NDIM + h * 8);
    }

    // ---- 2x-unrolled ping-pong main loop (static register roles) ----
    while (true) {
        EDGE_BODY(sA, dA, svA, dvA, sB, dB, svB, dvB);
        t += stride; if (t >= ntiles) break;
        EDGE_BODY(sB, dB, svB, dvB, sA, dA, svA, dvA);
        t += stride; if (t >= ntiles) break;
    }
}

// ---------------- fp32 fallback (ws too small; not expected) -----------------
__global__ __launch_bounds__(256) void edge_mlp_fp32_kernel(
    const float* __restrict__ x, const int* __restrict__ ei,
    const float* __restrict__ W1, const float* __restrict__ b1,
    const float* __restrict__ W2, const float* __restrict__ b2,
    float* __restrict__ out, int E)
{
    int e = blockIdx.x * blockDim.x + threadIdx.x;
    if (e >= E) return;
    int s = ei[e];
    int d = ei[E + e];
    const float* xs = x + (size_t)s * NDIM;
    const float* xd = x + (size_t)d * NDIM;
    float acc = b2[0];
    for (int j = 0; j < NDIM; j++) {
        float h = b1[j];
        for (int k = 0; k < NDIM; k++) {
            h += xs[k] * W1[j * FDIM + k] + xd[k] * W1[j * FDIM + 64 + k];
        }
        acc += W2[j] * (h > 0.f ? h : 0.f);
    }
    out[e] = acc;
}

extern "C" void kernel_launch(void* const* d_in, const int* in_sizes, int n_in,
                              void* d_out, int out_size, void* d_ws, size_t ws_size,
                              hipStream_t stream) {
    const float* x  = (const float*)d_in[0];
    const int*   ei = (const int*)d_in[1];
    const float* W1 = (const float*)d_in[2];
    const float* b1 = (const float*)d_in[3];
    const float* W2 = (const float*)d_in[4];
    const float* b2 = (const float*)d_in[5];
    float* out = (float*)d_out;
    const int E = out_size;
    const int N = in_sizes[0] / NDIM;

    const size_t tbl_bytes = (size_t)N * FDIM * sizeof(_Float16);   // 25.6 MB

    if (ws_size >= tbl_bytes && (N % 32) == 0 && (E % 64) == 0) {
        _Float16* Yab = (_Float16*)d_ws;

        const int nblocks = (N + 127) / 128;   // 4 waves x 32 nodes per block
        node_gemm_kernel<<<nblocks, 256, 0, stream>>>(x, W1, b1, Yab, N);

        // persistent edge kernel: ~4 tiles per wave
        const int ntiles  = E / 32;
        const int eblocks = (ntiles + 15) / 16;   // 4 waves, ~4 tiles each
        edge_combine_kernel<<<eblocks, 256, 0, stream>>>(
            Yab, ei, W2, b2, out, E);
    } else {
        edge_mlp_fp32_kernel<<<(E + 255) / 256, 256, 0, stream>>>(
            x, ei, W1, b1, W2, b2, out, E);
    }
}